// Round 4
// baseline (273.445 us; speedup 1.0000x reference)
//
#include <hip/hip_runtime.h>
#include <hip/hip_bf16.h>
#include <math.h>

typedef float  f32x4 __attribute__((ext_vector_type(4)));
typedef short  s16x8 __attribute__((ext_vector_type(8)));
typedef short  s16x4 __attribute__((ext_vector_type(4)));
typedef unsigned short u16x4 __attribute__((ext_vector_type(4)));

__device__ inline unsigned short bfc(float f){
  __hip_bfloat16 h = __float2bfloat16(f);
  unsigned short u; __builtin_memcpy(&u, &h, 2); return u;
}

__device__ inline f32x4 mfma16(s16x4 a, s16x4 b, f32x4 c){
#if __has_builtin(__builtin_amdgcn_mfma_f32_16x16x16_bf16)
  return __builtin_amdgcn_mfma_f32_16x16x16_bf16(a, b, c, 0, 0, 0);
#elif __has_builtin(__builtin_amdgcn_mfma_f32_16x16x16bf16_1k)
  return __builtin_amdgcn_mfma_f32_16x16x16bf16_1k(a, b, c, 0, 0, 0);
#else
  asm("v_mfma_f32_16x16x16_bf16 %0, %1, %2, %0" : "+v"(c) : "v"(a), "v"(b));
  return c;
#endif
}

// ---- q,k,v fp32 -> bf16 ----
__global__ __launch_bounds__(256) void cvt_qkv(const float* __restrict__ q, const float* __restrict__ k,
                                               const float* __restrict__ v, unsigned short* __restrict__ dst){
  int y = blockIdx.y;
  const float* src = y==0 ? q : (y==1 ? k : v);
  unsigned short* d = dst + (size_t)y * 2097152;
  int i = (blockIdx.x * 256 + threadIdx.x) * 4;
  f32x4 vv = *(const f32x4*)(src + i);
  u16x4 o = { bfc(vv.x), bfc(vv.y), bfc(vv.z), bfc(vv.w) };
  *(u16x4*)(d + i) = o;
}

// ---- weight cvt (4 weights) + mask->float addend (log2 domain) ----
__global__ __launch_bounds__(256) void wcvt(const float* __restrict__ w0, const float* __restrict__ w1,
                                            const float* __restrict__ w2, const float* __restrict__ w3,
                                            const unsigned char* __restrict__ mask,
                                            unsigned short* __restrict__ wb, float* __restrict__ mf){
  int y = blockIdx.y;
  int i = (blockIdx.x * 256 + threadIdx.x) * 4;
  if (y < 4){
    const float* src = y==0 ? w0 : y==1 ? w1 : y==2 ? w2 : w3;
    unsigned short* dst = wb + y * 262144;
    f32x4 v = *(const f32x4*)(src + i);
    u16x4 o = { bfc(v.x), bfc(v.y), bfc(v.z), bfc(v.w) };
    *(u16x4*)(dst + i) = o;
  } else if (i < 4096){
#pragma unroll
    for (int j = 0; j < 4; ++j)
      mf[i+j] = mask[i+j] ? -1.442695e9f : 0.0f;
  }
}

// ---- 3 projections (bf16 A) fused via z ----
__global__ __launch_bounds__(256) void proj_gemm(const unsigned short* __restrict__ Ab,
    const unsigned short* __restrict__ wb,
    const float* __restrict__ bq, const float* __restrict__ bk, const float* __restrict__ bv,
    unsigned short* __restrict__ pout){
  int z = blockIdx.z;
  const unsigned short* A = Ab + (size_t)z * 2097152;
  const unsigned short* W = wb + z * 262144;
  const float* bias = z==0 ? bq : (z==1 ? bk : bv);
  unsigned short* out = pout + (size_t)z * 2097152;

  int w = threadIdx.x >> 6, lane = threadIdx.x & 63;
  int lr = lane & 15, lg = lane >> 4;
  int arow = blockIdx.x * 64 + w * 16 + lr;
  int wrow0 = blockIdx.y * 64;
  f32x4 acc[4] = {}, acc2[4] = {};
  const unsigned short* Ap = A + (size_t)arow * 512 + lg * 8;
#pragma unroll 4
  for (int ks = 0; ks < 256; ks += 32){
    s16x8 af0 = *(const s16x8*)(Ap + ks);
    s16x8 af1 = *(const s16x8*)(Ap + 256 + ks);
#pragma unroll
    for (int n = 0; n < 4; ++n){
      const unsigned short* wr = W + (size_t)(wrow0 + n*16 + lr) * 512 + ks + lg * 8;
      s16x8 bf0 = *(const s16x8*)wr;
      s16x8 bf1 = *(const s16x8*)(wr + 256);
      acc[n]  = __builtin_amdgcn_mfma_f32_16x16x32_bf16(af0, bf0, acc[n],  0, 0, 0);
      acc2[n] = __builtin_amdgcn_mfma_f32_16x16x32_bf16(af1, bf1, acc2[n], 0, 0, 0);
    }
  }
  int orow = blockIdx.x * 64 + w * 16 + lg * 4;
#pragma unroll
  for (int n = 0; n < 4; ++n){
    int col = wrow0 + n * 16 + lr;
    float bv_ = bias[col];
#pragma unroll
    for (int r = 0; r < 4; ++r)
      out[(size_t)(orow + r) * 512 + col] = bfc(acc[n][r] + acc2[n][r] + bv_);
  }
}

// ---- Vt[bh][d=64][key=2048] = V_h[key][d] ----
__global__ __launch_bounds__(256) void vtrans(const unsigned short* __restrict__ Pv,
                                              unsigned short* __restrict__ Vt){
  int kt = blockIdx.x, bh = blockIdx.y;
  int b = bh >> 3, h = bh & 7;
  __shared__ unsigned short t[64][65];
  const unsigned short* src = Pv + (size_t)(b*2048 + h*256)*512 + kt*4096;
  for (int i = threadIdx.x; i < 4096; i += 256){ int r = i >> 6, c = i & 63; t[r][c] = src[i]; }
  __syncthreads();
  unsigned short* dst = Vt + (size_t)bh*131072 + kt*64;
  for (int i = threadIdx.x; i < 4096; i += 256){ int d = i >> 6, kk = i & 63; dst[(size_t)d*2048 + kk] = t[kk][d]; }
}

// ---- flash attention: zero-LDS main loop ----
// QK^T swapped (16x16x32): S^T C-frag = (q=lane&15, key16=lg*4+r) — which IS the
// B-frag layout of 16x16x16 (k=lg*4+j). PV uses mfma16 per 16-key block with
// P packed in-register. 8 waves = 2 q-subtiles x 4 KV quarters; LDS only for merge.
__global__ __launch_bounds__(512) void flash(const unsigned short* __restrict__ Pq,
                                             const unsigned short* __restrict__ Pk,
                                             const unsigned short* __restrict__ Vt,
                                             const float* __restrict__ mf,
                                             unsigned short* __restrict__ attnOut){
  int qt = blockIdx.x;          // 0..63 (32 q-rows each)
  int bh = blockIdx.y;          // 0..15
  int b = bh >> 3, h = bh & 7;
  int w = threadIdx.x >> 6;     // 0..7
  int wq = w & 1, wk = w >> 1;  // 2 q-subtiles x 4 KV quarters
  int lane = threadIdx.x & 63;
  int lr = lane & 15, lg = lane >> 4;

  const unsigned short* Qh  = Pq + (size_t)(b*2048 + h*256)*512;
  const unsigned short* Kh  = Pk + (size_t)(b*2048 + h*256)*512 + (size_t)wk*32768;  // +512 keys
  const unsigned short* Vth = Vt + (size_t)bh*131072 + wk*512;
  const float* mrow = mf + b*2048 + wk*512;

  __shared__ float mbuf[2][3][16];
  __shared__ float lbuf[2][3][16];
  __shared__ float obuf[2][3][64][20];   // [wq][wk-1][lane][16 used], pad 20

  int q = qt*32 + wq*16 + lr;
  s16x8 qf0 = *(const s16x8*)(Qh + (size_t)q*64 + lg*8);
  s16x8 qf1 = *(const s16x8*)(Qh + (size_t)q*64 + 32 + lg*8);

  float m2 = -INFINITY, l = 0.f;
  f32x4 accT[4] = {};   // accT[nd][r] = O^T[d=nd*16+lg*4+r][q=lr]

  for (int kt = 0; kt < 512; kt += 64){
    float s2[4][4];
    // --- S^T = K Q^T (scale*log2e + mask addend fused) ---
    __builtin_amdgcn_s_setprio(1);
#pragma unroll
    for (int n = 0; n < 4; ++n){
      const unsigned short* kr = Kh + (size_t)(kt + n*16 + lr)*64 + lg*8;
      s16x8 kf0 = *(const s16x8*)kr;
      s16x8 kf1 = *(const s16x8*)(kr + 32);
      f32x4 a = {};
      a = __builtin_amdgcn_mfma_f32_16x16x32_bf16(kf0, qf0, a, 0, 0, 0);
      a = __builtin_amdgcn_mfma_f32_16x16x32_bf16(kf1, qf1, a, 0, 0, 0);
      f32x4 mv = *(const f32x4*)(mrow + kt + n*16 + lg*4);
#pragma unroll
      for (int r = 0; r < 4; ++r)
        s2[n][r] = __builtin_fmaf(a[r], 0.18033688f, mv[r]);   // log2e/8
    }
    __builtin_amdgcn_s_setprio(0);
    // --- rowmax: in-lane tree + 2 shfls (per-q group {lr+16g}) ---
    float t0 = fmaxf(fmaxf(s2[0][0], s2[0][1]), fmaxf(s2[0][2], s2[0][3]));
    float t1 = fmaxf(fmaxf(s2[1][0], s2[1][1]), fmaxf(s2[1][2], s2[1][3]));
    float t2 = fmaxf(fmaxf(s2[2][0], s2[2][1]), fmaxf(s2[2][2], s2[2][3]));
    float t3 = fmaxf(fmaxf(s2[3][0], s2[3][1]), fmaxf(s2[3][2], s2[3][3]));
    float rm = fmaxf(fmaxf(t0, t1), fmaxf(t2, t3));
    rm = fmaxf(rm, __shfl_xor(rm, 16));
    rm = fmaxf(rm, __shfl_xor(rm, 32));
    // --- defer-max: rescale only when max grew > 8 nats ---
    if (!__all(rm <= m2 + 11.54f)){
      float mn = fmaxf(m2, rm);
      float al = __builtin_amdgcn_exp2f(m2 - mn);
      l *= al;
#pragma unroll
      for (int nd = 0; nd < 4; ++nd)
#pragma unroll
        for (int r = 0; r < 4; ++r) accT[nd][r] *= al;
      m2 = mn;
    }
    // --- P = exp2(S2 - m2): pack in-register as 16x16x16 B-frags ---
    s16x4 pf[4];
#pragma unroll
    for (int n = 0; n < 4; ++n){
      float p0 = __builtin_amdgcn_exp2f(s2[n][0] - m2);
      float p1 = __builtin_amdgcn_exp2f(s2[n][1] - m2);
      float p2 = __builtin_amdgcn_exp2f(s2[n][2] - m2);
      float p3 = __builtin_amdgcn_exp2f(s2[n][3] - m2);
      l += (p0 + p1) + (p2 + p3);
      pf[n] = (s16x4){ (short)bfc(p0), (short)bfc(p1), (short)bfc(p2), (short)bfc(p3) };
    }
    // --- O^T += V^T P^T  (16x16x16, A=V^T frag row=d,k=key; B=pf) ---
    __builtin_amdgcn_s_setprio(1);
#pragma unroll
    for (int n = 0; n < 4; ++n){
#pragma unroll
      for (int nd = 0; nd < 4; ++nd){
        s16x4 vf = *(const s16x4*)(Vth + (size_t)(nd*16 + lr)*2048 + kt + n*16 + lg*4);
        accT[nd] = mfma16(vf, pf[n], accT[nd]);
      }
    }
    __builtin_amdgcn_s_setprio(0);
  }
  // --- in-wave l reduce over the 4-lane q-group ---
  float lt = l + __shfl_xor(l, 16);
  lt += __shfl_xor(lt, 32);
  // --- cross-quarter merge via LDS ---
  if (wk != 0){
    int j = wk - 1;
    if (lg == 0){ mbuf[wq][j][lr] = m2; lbuf[wq][j][lr] = lt; }
#pragma unroll
    for (int nd = 0; nd < 4; ++nd)
      *(f32x4*)&obuf[wq][j][lane][nd*4] = accT[nd];
  }
  __syncthreads();
  if (wk == 0){
    float mj[3], lj[3];
    float mM = m2;
#pragma unroll
    for (int j = 0; j < 3; ++j){
      mj[j] = mbuf[wq][j][lr];
      lj[j] = lbuf[wq][j][lr];
      mM = fmaxf(mM, mj[j]);
    }
    float a0 = __builtin_amdgcn_exp2f(m2 - mM);
    float aj[3];
    float ltot = lt * a0;
#pragma unroll
    for (int j = 0; j < 3; ++j){
      aj[j] = __builtin_amdgcn_exp2f(mj[j] - mM);
      ltot += lj[j] * aj[j];
    }
    float inv = 1.f / ltot;
    unsigned short* orow = attnOut + (size_t)(b*2048 + q)*512 + h*64;
#pragma unroll
    for (int nd = 0; nd < 4; ++nd){
      f32x4 o = accT[nd] * a0;
#pragma unroll
      for (int j = 0; j < 3; ++j){
        f32x4 oj = *(const f32x4*)&obuf[wq][j][lane][nd*4];
        o += oj * aj[j];
      }
      u16x4 ov = { bfc(o[0]*inv), bfc(o[1]*inv), bfc(o[2]*inv), bfc(o[3]*inv) };
      *(u16x4*)(orow + nd*16 + lg*4) = ov;
    }
  }
}

// ---- output projection: bf16 A @ Wm^T + bm -> fp32 ----
__global__ __launch_bounds__(256) void gemm_out(const unsigned short* __restrict__ A,
                                                const unsigned short* __restrict__ W,
                                                const float* __restrict__ bias,
                                                float* __restrict__ out){
  int w = threadIdx.x >> 6, lane = threadIdx.x & 63;
  int lr = lane & 15, lg = lane >> 4;
  int arow = blockIdx.x * 64 + w * 16 + lr;
  int wrow0 = blockIdx.y * 64;
  f32x4 acc[4] = {}, acc2[4] = {};
  const unsigned short* Ap = A + (size_t)arow * 512 + lg * 8;
#pragma unroll 4
  for (int ks = 0; ks < 256; ks += 32){
    s16x8 af0 = *(const s16x8*)(Ap + ks);
    s16x8 af1 = *(const s16x8*)(Ap + 256 + ks);
#pragma unroll
    for (int n = 0; n < 4; ++n){
      const unsigned short* wr = W + (size_t)(wrow0 + n*16 + lr) * 512 + ks + lg * 8;
      s16x8 bf0 = *(const s16x8*)wr;
      s16x8 bf1 = *(const s16x8*)(wr + 256);
      acc[n]  = __builtin_amdgcn_mfma_f32_16x16x32_bf16(af0, bf0, acc[n],  0, 0, 0);
      acc2[n] = __builtin_amdgcn_mfma_f32_16x16x32_bf16(af1, bf1, acc2[n], 0, 0, 0);
    }
  }
  int orow = blockIdx.x * 64 + w * 16 + lg * 4;
#pragma unroll
  for (int n = 0; n < 4; ++n){
    int col = wrow0 + n * 16 + lr;
    float bv_ = bias[col];
#pragma unroll
    for (int r = 0; r < 4; ++r)
      out[(size_t)(orow + r) * 512 + col] = acc[n][r] + acc2[n][r] + bv_;
  }
}

extern "C" void kernel_launch(void* const* d_in, const int* in_sizes, int n_in,
                              void* d_out, int out_size, void* d_ws, size_t ws_size,
                              hipStream_t stream) {
  const float* q  = (const float*)d_in[0];
  const float* k  = (const float*)d_in[1];
  const float* v  = (const float*)d_in[2];
  const unsigned char* mask = (const unsigned char*)d_in[3];
  const float* Wq = (const float*)d_in[4];
  const float* Wk = (const float*)d_in[5];
  const float* Wv = (const float*)d_in[6];
  const float* Wm = (const float*)d_in[7];
  const float* bq = (const float*)d_in[8];
  const float* bk = (const float*)d_in[9];
  const float* bv = (const float*)d_in[10];
  const float* bm = (const float*)d_in[11];

  unsigned short* ws = (unsigned short*)d_ws;
  unsigned short* WB   = ws;                       // 4 x 262144
  float*          MF   = (float*)(ws + 1048576);   // 4096 floats
  unsigned short* QKVB = ws + 1056768;             // 3 x 2097152
  unsigned short* PQ   = ws + 7348224;             // 3 x 2097152
  unsigned short* VT   = ws + 13639680;            // 2097152
  unsigned short* AO   = ws + 15736832;            // 2097152

  cvt_qkv<<<dim3(2048, 3), 256, 0, stream>>>(q, k, v, QKVB);
  wcvt<<<dim3(256, 5), 256, 0, stream>>>(Wq, Wk, Wv, Wm, mask, WB, MF);
  proj_gemm<<<dim3(64, 8, 3), 256, 0, stream>>>(QKVB, WB, bq, bk, bv, PQ);
  vtrans<<<dim3(32, 16), 256, 0, stream>>>(PQ + 2*2097152, VT);
  flash<<<dim3(64, 16), 512, 0, stream>>>(PQ, PQ + 2097152, VT, MF, AO);
  gemm_out<<<dim3(64, 8), 256, 0, stream>>>(AO, WB + 3*262144, bm, (float*)d_out);
}

// Round 5
// 160.763 us; speedup vs baseline: 1.7009x; 1.7009x over previous
//
#include <hip/hip_runtime.h>
#include <hip/hip_bf16.h>
#include <math.h>

typedef float  f32x4 __attribute__((ext_vector_type(4)));
typedef short  s16x8 __attribute__((ext_vector_type(8)));
typedef short  s16x4 __attribute__((ext_vector_type(4)));
typedef unsigned short u16x4 __attribute__((ext_vector_type(4)));

__device__ inline unsigned short bfc(float f){
  __hip_bfloat16 h = __float2bfloat16(f);
  unsigned short u; __builtin_memcpy(&u, &h, 2); return u;
}

__device__ inline f32x4 mfma16(s16x4 a, s16x4 b, f32x4 c){
#if __has_builtin(__builtin_amdgcn_mfma_f32_16x16x16_bf16)
  return __builtin_amdgcn_mfma_f32_16x16x16_bf16(a, b, c, 0, 0, 0);
#elif __has_builtin(__builtin_amdgcn_mfma_f32_16x16x16bf16_1k)
  return __builtin_amdgcn_mfma_f32_16x16x16bf16_1k(a, b, c, 0, 0, 0);
#else
  asm("v_mfma_f32_16x16x16_bf16 %0, %1, %2, %0" : "+v"(c) : "v"(a), "v"(b));
  return c;
#endif
}

__device__ inline void gl_lds16(const unsigned short* g, unsigned short* l){
  __builtin_amdgcn_global_load_lds(
      (const __attribute__((address_space(1))) unsigned int*)g,
      (__attribute__((address_space(3))) unsigned int*)l, 16, 0, 0);
}

// ---- q,k,v fp32 -> bf16 ----
__global__ __launch_bounds__(256) void cvt_qkv(const float* __restrict__ q, const float* __restrict__ k,
                                               const float* __restrict__ v, unsigned short* __restrict__ dst){
  int y = blockIdx.y;
  const float* src = y==0 ? q : (y==1 ? k : v);
  unsigned short* d = dst + (size_t)y * 2097152;
  int i = (blockIdx.x * 256 + threadIdx.x) * 4;
  f32x4 vv = *(const f32x4*)(src + i);
  u16x4 o = { bfc(vv.x), bfc(vv.y), bfc(vv.z), bfc(vv.w) };
  *(u16x4*)(d + i) = o;
}

// ---- weight cvt (4 weights) + mask->float addend (log2 domain) ----
__global__ __launch_bounds__(256) void wcvt(const float* __restrict__ w0, const float* __restrict__ w1,
                                            const float* __restrict__ w2, const float* __restrict__ w3,
                                            const unsigned char* __restrict__ mask,
                                            unsigned short* __restrict__ wb, float* __restrict__ mf){
  int y = blockIdx.y;
  int i = (blockIdx.x * 256 + threadIdx.x) * 4;
  if (y < 4){
    const float* src = y==0 ? w0 : y==1 ? w1 : y==2 ? w2 : w3;
    unsigned short* dst = wb + y * 262144;
    f32x4 v = *(const f32x4*)(src + i);
    u16x4 o = { bfc(v.x), bfc(v.y), bfc(v.z), bfc(v.w) };
    *(u16x4*)(dst + i) = o;
  } else if (i < 4096){
#pragma unroll
    for (int j = 0; j < 4; ++j)
      mf[i+j] = mask[i+j] ? -1.442695e9f : 0.0f;
  }
}

// ---- 3 projections (bf16 A) fused via z ----
__global__ __launch_bounds__(256) void proj_gemm(const unsigned short* __restrict__ Ab,
    const unsigned short* __restrict__ wb,
    const float* __restrict__ bq, const float* __restrict__ bk, const float* __restrict__ bv,
    unsigned short* __restrict__ pout){
  int z = blockIdx.z;
  const unsigned short* A = Ab + (size_t)z * 2097152;
  const unsigned short* W = wb + z * 262144;
  const float* bias = z==0 ? bq : (z==1 ? bk : bv);
  unsigned short* out = pout + (size_t)z * 2097152;

  int w = threadIdx.x >> 6, lane = threadIdx.x & 63;
  int lr = lane & 15, lg = lane >> 4;
  int arow = blockIdx.x * 64 + w * 16 + lr;
  int wrow0 = blockIdx.y * 64;
  f32x4 acc[4] = {}, acc2[4] = {};
  const unsigned short* Ap = A + (size_t)arow * 512 + lg * 8;
#pragma unroll 4
  for (int ks = 0; ks < 256; ks += 32){
    s16x8 af0 = *(const s16x8*)(Ap + ks);
    s16x8 af1 = *(const s16x8*)(Ap + 256 + ks);
#pragma unroll
    for (int n = 0; n < 4; ++n){
      const unsigned short* wr = W + (size_t)(wrow0 + n*16 + lr) * 512 + ks + lg * 8;
      s16x8 bf0 = *(const s16x8*)wr;
      s16x8 bf1 = *(const s16x8*)(wr + 256);
      acc[n]  = __builtin_amdgcn_mfma_f32_16x16x32_bf16(af0, bf0, acc[n],  0, 0, 0);
      acc2[n] = __builtin_amdgcn_mfma_f32_16x16x32_bf16(af1, bf1, acc2[n], 0, 0, 0);
    }
  }
  int orow = blockIdx.x * 64 + w * 16 + lg * 4;
#pragma unroll
  for (int n = 0; n < 4; ++n){
    int col = wrow0 + n * 16 + lr;
    float bv_ = bias[col];
#pragma unroll
    for (int r = 0; r < 4; ++r)
      out[(size_t)(orow + r) * 512 + col] = bfc(acc[n][r] + acc2[n][r] + bv_);
  }
}

// ---- Vt[bh][d=64][key=2048] = V_h[key][d] ----
__global__ __launch_bounds__(256) void vtrans(const unsigned short* __restrict__ Pv,
                                              unsigned short* __restrict__ Vt){
  int kt = blockIdx.x, bh = blockIdx.y;
  int b = bh >> 3, h = bh & 7;
  __shared__ unsigned short t[64][65];
  const unsigned short* src = Pv + (size_t)(b*2048 + h*256)*512 + kt*4096;
  for (int i = threadIdx.x; i < 4096; i += 256){ int r = i >> 6, c = i & 63; t[r][c] = src[i]; }
  __syncthreads();
  unsigned short* dst = Vt + (size_t)bh*131072 + kt*64;
  for (int i = threadIdx.x; i < 4096; i += 256){ int d = i >> 6, kk = i & 63; dst[(size_t)d*2048 + kk] = t[kk][d]; }
}

// ---- flash attention: LDS-staged K/V tiles, coalesced global_load_lds ----
// Block = 64 q-rows x 4 waves (wave owns 16 rows), one bh; 32 tiles of 64 keys.
// K tile [64 key][64 d], V^T tile [64 d][64 key]; both 128B rows with XOR swizzle
// byte^=( (row&7)*16 ), applied via pre-swizzled GLOBAL source (linear LDS dest).
// QK^T swapped (16x16x32) -> S^T C-frag (q=lr, key=lg*4+r) == 16x16x16 B-frag ->
// PV via mfma16 with in-register P. Double-buffered staging, prefetch-first.
__global__ __launch_bounds__(256) void flash(const unsigned short* __restrict__ Pq,
                                             const unsigned short* __restrict__ Pk,
                                             const unsigned short* __restrict__ Vt,
                                             const float* __restrict__ mf,
                                             unsigned short* __restrict__ attnOut){
  int qt = blockIdx.x;          // 0..31
  int bh = blockIdx.y;          // 0..15
  int b = bh >> 3, h = bh & 7;
  int w = threadIdx.x >> 6;     // 0..3
  int lane = threadIdx.x & 63;
  int lr = lane & 15, lg = lane >> 4;

  const unsigned short* Qh  = Pq + (size_t)(b*2048 + h*256)*512;  // [2048][64]
  const unsigned short* Kh  = Pk + (size_t)(b*2048 + h*256)*512;  // [2048][64]
  const unsigned short* Vth = Vt + (size_t)bh*131072;             // [64][2048]
  const float* mrow = mf + b*2048;

  __shared__ unsigned short ktile[2][4096];   // [64][64] bf16, swizzled rows
  __shared__ unsigned short vtile[2][4096];   // [64][64] bf16, swizzled rows

  // staging source swizzle: lane covers row (8i + lane>>3), 16B chunk (lane&7)
  int lrow = lane >> 3;                       // 0..7
  int lcol = ((lane & 7) ^ lrow) * 8;         // shorts, pre-swizzled source col

  int q = qt*64 + w*16 + lr;
  s16x8 qf0 = *(const s16x8*)(Qh + (size_t)q*64 + lg*8);
  s16x8 qf1 = *(const s16x8*)(Qh + (size_t)q*64 + 32 + lg*8);

  float m2 = -INFINITY, l = 0.f;
  f32x4 accT[4] = {};   // accT[nd][r] = O^T[d=nd*16+lg*4+r][q=lr]

  int swz = (lr & 7) * 16;                    // read-side byte swizzle

#define STAGE(dstbuf, kk0) { \
    int i0 = 2*w, i1 = 2*w + 1; \
    gl_lds16(Kh  + (size_t)((kk0) + 8*i0 + lrow)*64 + lcol, (unsigned short*)((char*)ktile[dstbuf] + i0*1024)); \
    gl_lds16(Kh  + (size_t)((kk0) + 8*i1 + lrow)*64 + lcol, (unsigned short*)((char*)ktile[dstbuf] + i1*1024)); \
    gl_lds16(Vth + (size_t)(8*i0 + lrow)*2048 + (kk0) + lcol, (unsigned short*)((char*)vtile[dstbuf] + i0*1024)); \
    gl_lds16(Vth + (size_t)(8*i1 + lrow)*2048 + (kk0) + lcol, (unsigned short*)((char*)vtile[dstbuf] + i1*1024)); }

  STAGE(0, 0)
  __syncthreads();
  int cur = 0;

  for (int t = 0; t < 32; ++t){
    int k0 = t * 64;
    if (t < 31) STAGE(cur ^ 1, k0 + 64)

    const char* kb = (const char*)ktile[cur];
    const char* vb = (const char*)vtile[cur];

    // --- S^T = K Q^T (scale*log2e + mask addend fused) ---
    float s2[4][4];
    __builtin_amdgcn_s_setprio(1);
#pragma unroll
    for (int n = 0; n < 4; ++n){
      int krow = n*16 + lr;
      s16x8 kf0 = *(const s16x8*)(kb + krow*128 + ((lg*16) ^ swz));
      s16x8 kf1 = *(const s16x8*)(kb + krow*128 + ((64 + lg*16) ^ swz));
      f32x4 a = {};
      a = __builtin_amdgcn_mfma_f32_16x16x32_bf16(kf0, qf0, a, 0, 0, 0);
      a = __builtin_amdgcn_mfma_f32_16x16x32_bf16(kf1, qf1, a, 0, 0, 0);
      f32x4 mv = *(const f32x4*)(mrow + k0 + n*16 + lg*4);
#pragma unroll
      for (int r = 0; r < 4; ++r)
        s2[n][r] = __builtin_fmaf(a[r], 0.18033688f, mv[r]);   // log2e/8
    }
    __builtin_amdgcn_s_setprio(0);

    // --- rowmax: in-lane tree + 2 shfls ---
    float t0 = fmaxf(fmaxf(s2[0][0], s2[0][1]), fmaxf(s2[0][2], s2[0][3]));
    float t1 = fmaxf(fmaxf(s2[1][0], s2[1][1]), fmaxf(s2[1][2], s2[1][3]));
    float t2 = fmaxf(fmaxf(s2[2][0], s2[2][1]), fmaxf(s2[2][2], s2[2][3]));
    float t3 = fmaxf(fmaxf(s2[3][0], s2[3][1]), fmaxf(s2[3][2], s2[3][3]));
    float rm = fmaxf(fmaxf(t0, t1), fmaxf(t2, t3));
    rm = fmaxf(rm, __shfl_xor(rm, 16));
    rm = fmaxf(rm, __shfl_xor(rm, 32));
    // --- defer-max rescale ---
    if (!__all(rm <= m2 + 11.54f)){
      float mn = fmaxf(m2, rm);
      float al = __builtin_amdgcn_exp2f(m2 - mn);
      l *= al;
#pragma unroll
      for (int nd = 0; nd < 4; ++nd)
#pragma unroll
        for (int r = 0; r < 4; ++r) accT[nd][r] *= al;
      m2 = mn;
    }
    // --- P = exp2(S2 - m2): in-register 16x16x16 B-frags ---
    s16x4 pf[4];
#pragma unroll
    for (int n = 0; n < 4; ++n){
      float p0 = __builtin_amdgcn_exp2f(s2[n][0] - m2);
      float p1 = __builtin_amdgcn_exp2f(s2[n][1] - m2);
      float p2 = __builtin_amdgcn_exp2f(s2[n][2] - m2);
      float p3 = __builtin_amdgcn_exp2f(s2[n][3] - m2);
      l += (p0 + p1) + (p2 + p3);
      pf[n] = (s16x4){ (short)bfc(p0), (short)bfc(p1), (short)bfc(p2), (short)bfc(p3) };
    }
    // --- O^T += V^T P^T (A = V^T frag from LDS, B = pf) ---
    __builtin_amdgcn_s_setprio(1);
#pragma unroll
    for (int n = 0; n < 4; ++n){
#pragma unroll
      for (int nd = 0; nd < 4; ++nd){
        int vrow = nd*16 + lr;
        s16x4 vf = *(const s16x4*)(vb + vrow*128 + ((n*32 + lg*8) ^ swz));
        accT[nd] = mfma16(vf, pf[n], accT[nd]);
      }
    }
    __builtin_amdgcn_s_setprio(0);

    __syncthreads();   // drains vmcnt (stage done) + protects buffer swap
    cur ^= 1;
  }
#undef STAGE

  // --- l reduce + normalize + write (each wave owns its rows; no merge) ---
  float lt = l + __shfl_xor(l, 16);
  lt += __shfl_xor(lt, 32);
  float inv = (lt > 0.f) ? 1.f / lt : 0.f;
  unsigned short* orow = attnOut + (size_t)(b*2048 + q)*512 + h*64;
#pragma unroll
  for (int nd = 0; nd < 4; ++nd){
    u16x4 ov = { bfc(accT[nd][0]*inv), bfc(accT[nd][1]*inv),
                 bfc(accT[nd][2]*inv), bfc(accT[nd][3]*inv) };
    *(u16x4*)(orow + nd*16 + lg*4) = ov;
  }
}

// ---- output projection: bf16 A @ Wm^T + bm -> fp32 ----
__global__ __launch_bounds__(256) void gemm_out(const unsigned short* __restrict__ A,
                                                const unsigned short* __restrict__ W,
                                                const float* __restrict__ bias,
                                                float* __restrict__ out){
  int w = threadIdx.x >> 6, lane = threadIdx.x & 63;
  int lr = lane & 15, lg = lane >> 4;
  int arow = blockIdx.x * 64 + w * 16 + lr;
  int wrow0 = blockIdx.y * 64;
  f32x4 acc[4] = {}, acc2[4] = {};
  const unsigned short* Ap = A + (size_t)arow * 512 + lg * 8;
#pragma unroll 4
  for (int ks = 0; ks < 256; ks += 32){
    s16x8 af0 = *(const s16x8*)(Ap + ks);
    s16x8 af1 = *(const s16x8*)(Ap + 256 + ks);
#pragma unroll
    for (int n = 0; n < 4; ++n){
      const unsigned short* wr = W + (size_t)(wrow0 + n*16 + lr) * 512 + ks + lg * 8;
      s16x8 bf0 = *(const s16x8*)wr;
      s16x8 bf1 = *(const s16x8*)(wr + 256);
      acc[n]  = __builtin_amdgcn_mfma_f32_16x16x32_bf16(af0, bf0, acc[n],  0, 0, 0);
      acc2[n] = __builtin_amdgcn_mfma_f32_16x16x32_bf16(af1, bf1, acc2[n], 0, 0, 0);
    }
  }
  int orow = blockIdx.x * 64 + w * 16 + lg * 4;
#pragma unroll
  for (int n = 0; n < 4; ++n){
    int col = wrow0 + n * 16 + lr;
    float bv_ = bias[col];
#pragma unroll
    for (int r = 0; r < 4; ++r)
      out[(size_t)(orow + r) * 512 + col] = acc[n][r] + acc2[n][r] + bv_;
  }
}

extern "C" void kernel_launch(void* const* d_in, const int* in_sizes, int n_in,
                              void* d_out, int out_size, void* d_ws, size_t ws_size,
                              hipStream_t stream) {
  const float* q  = (const float*)d_in[0];
  const float* k  = (const float*)d_in[1];
  const float* v  = (const float*)d_in[2];
  const unsigned char* mask = (const unsigned char*)d_in[3];
  const float* Wq = (const float*)d_in[4];
  const float* Wk = (const float*)d_in[5];
  const float* Wv = (const float*)d_in[6];
  const float* Wm = (const float*)d_in[7];
  const float* bq = (const float*)d_in[8];
  const float* bk = (const float*)d_in[9];
  const float* bv = (const float*)d_in[10];
  const float* bm = (const float*)d_in[11];

  unsigned short* ws = (unsigned short*)d_ws;
  unsigned short* WB   = ws;                       // 4 x 262144
  float*          MF   = (float*)(ws + 1048576);   // 4096 floats
  unsigned short* QKVB = ws + 1056768;             // 3 x 2097152
  unsigned short* PQ   = ws + 7348224;             // 3 x 2097152
  unsigned short* VT   = ws + 13639680;            // 2097152
  unsigned short* AO   = ws + 15736832;            // 2097152

  cvt_qkv<<<dim3(2048, 3), 256, 0, stream>>>(q, k, v, QKVB);
  wcvt<<<dim3(256, 5), 256, 0, stream>>>(Wq, Wk, Wv, Wm, mask, WB, MF);
  proj_gemm<<<dim3(64, 8, 3), 256, 0, stream>>>(QKVB, WB, bq, bk, bv, PQ);
  vtrans<<<dim3(32, 16), 256, 0, stream>>>(PQ + 2*2097152, VT);
  flash<<<dim3(32, 16), 256, 0, stream>>>(PQ, PQ + 2097152, VT, MF, AO);
  gemm_out<<<dim3(64, 8), 256, 0, stream>>>(AO, WB + 3*262144, bm, (float*)d_out);
}

// Round 7
// 84.481 us; speedup vs baseline: 3.2368x; 1.9030x over previous
//
#include <hip/hip_runtime.h>
#include <hip/hip_bf16.h>
#include <math.h>

typedef float  f32x4 __attribute__((ext_vector_type(4)));
typedef short  s16x8 __attribute__((ext_vector_type(8)));
typedef short  s16x4 __attribute__((ext_vector_type(4)));
typedef unsigned short u16x4 __attribute__((ext_vector_type(4)));

__device__ inline unsigned short bfc(float f){
  __hip_bfloat16 h = __float2bfloat16(f);
  unsigned short u; __builtin_memcpy(&u, &h, 2); return u;
}

__device__ inline f32x4 mfma16(s16x4 a, s16x4 b, f32x4 c){
#if __has_builtin(__builtin_amdgcn_mfma_f32_16x16x16_bf16)
  return __builtin_amdgcn_mfma_f32_16x16x16_bf16(a, b, c, 0, 0, 0);
#elif __has_builtin(__builtin_amdgcn_mfma_f32_16x16x16bf16_1k)
  return __builtin_amdgcn_mfma_f32_16x16x16bf16_1k(a, b, c, 0, 0, 0);
#else
  asm("v_mfma_f32_16x16x16_bf16 %0, %1, %2, %0" : "+v"(c) : "v"(a), "v"(b));
  return c;
#endif
}

__device__ inline void gl_lds16(const unsigned short* g, unsigned short* l){
  __builtin_amdgcn_global_load_lds(
      (const __attribute__((address_space(1))) unsigned int*)g,
      (__attribute__((address_space(3))) unsigned int*)l, 16, 0, 0);
}

// ---- q,k,v fp32 -> bf16, written in MFMA-A-fragment-packed order ----
// Ap flat index: ((rt*16 + kc)*64 + lane)*8 ; element = A[rt*16+(lane&15)][kc*32+(lane>>4)*8+j]
__global__ __launch_bounds__(256) void cvt_qkv(const float* __restrict__ q, const float* __restrict__ k,
                                               const float* __restrict__ v, unsigned short* __restrict__ dst){
  int z = blockIdx.y;
  const float* src = z==0 ? q : (z==1 ? k : v);
  unsigned short* d = dst + (size_t)z * 2097152;
  int t = blockIdx.x * 256 + threadIdx.x;     // 0..262143
  int r = t >> 6, g = t & 63;
  const float* sp = src + (size_t)r * 512 + g * 8;
  f32x4 a0 = *(const f32x4*)sp;
  f32x4 a1 = *(const f32x4*)(sp + 4);
  s16x8 o = { (short)bfc(a0.x),(short)bfc(a0.y),(short)bfc(a0.z),(short)bfc(a0.w),
              (short)bfc(a1.x),(short)bfc(a1.y),(short)bfc(a1.z),(short)bfc(a1.w) };
  size_t off = ((size_t)(((r>>4)*16 + (g>>2))*64 + (g&3)*16 + (r&15))) * 8;
  *(s16x8*)(d + off) = o;
}

// ---- 4 weights -> bf16 B-fragment-packed + mask->float addend ----
__global__ __launch_bounds__(256) void wcvt(const float* __restrict__ w0, const float* __restrict__ w1,
                                            const float* __restrict__ w2, const float* __restrict__ w3,
                                            const unsigned char* __restrict__ mask,
                                            unsigned short* __restrict__ wb, float* __restrict__ mf){
  int y = blockIdx.y;
  int t = blockIdx.x * 256 + threadIdx.x;
  if (y < 4){
    const float* src = y==0 ? w0 : y==1 ? w1 : y==2 ? w2 : w3;
    int c = t >> 6, g = t & 63;
    const float* sp = src + (size_t)c * 512 + g * 8;
    f32x4 a0 = *(const f32x4*)sp;
    f32x4 a1 = *(const f32x4*)(sp + 4);
    s16x8 o = { (short)bfc(a0.x),(short)bfc(a0.y),(short)bfc(a0.z),(short)bfc(a0.w),
                (short)bfc(a1.x),(short)bfc(a1.y),(short)bfc(a1.z),(short)bfc(a1.w) };
    size_t off = ((size_t)(((c>>4)*16 + (g>>2))*64 + (g&3)*16 + (c&15))) * 8;
    *(s16x8*)(wb + y*262144 + off) = o;
  } else if (t < 4096){
    mf[t] = mask[t] ? -1.442695e9f : 0.0f;
  }
}

// ---- 3 projections, all-coalesced packed operands, no LDS, no barriers ----
// FIX R6->R7: packed tile strides are rt*8192 / bn*32768 (the *8 innermost dim
// was dropped last round -> garbage reads beyond the first tile).
__global__ __launch_bounds__(256) void proj_gemm(const unsigned short* __restrict__ Ap,
    const unsigned short* __restrict__ Wp,
    const float* __restrict__ bq, const float* __restrict__ bk, const float* __restrict__ bv,
    unsigned short* __restrict__ pout){
  int z = blockIdx.z;
  const unsigned short* A = Ap + (size_t)z * 2097152;
  const unsigned short* W = Wp + (size_t)z * 262144;
  const float* bias = z==0 ? bq : (z==1 ? bk : bv);
  unsigned short* out = pout + (size_t)z * 2097152;

  int w = threadIdx.x >> 6, lane = threadIdx.x & 63;
  int lr = lane & 15, lg = lane >> 4;
  int rt = blockIdx.x * 4 + w;          // 16-row tile index
  int bn = blockIdx.y;                  // 64-col tile

  f32x4 acc[4] = {};
  const unsigned short* Abase = A + ((size_t)rt*8192 + lane*8);
  const unsigned short* Wbase = W + ((size_t)bn*32768 + lane*8);
#pragma unroll 4
  for (int kc = 0; kc < 16; ++kc){
    s16x8 af = *(const s16x8*)(Abase + kc*512);
#pragma unroll
    for (int n = 0; n < 4; ++n){
      s16x8 bf = *(const s16x8*)(Wbase + ((size_t)n*16 + kc)*512);
      acc[n] = __builtin_amdgcn_mfma_f32_16x16x32_bf16(af, bf, acc[n], 0, 0, 0);
    }
  }
  int orow = rt*16 + lg*4;
#pragma unroll
  for (int n = 0; n < 4; ++n){
    int col = bn*64 + n*16 + lr;
    float bv_ = bias[col];
#pragma unroll
    for (int r = 0; r < 4; ++r)
      out[(size_t)(orow + r)*512 + col] = bfc(acc[n][r] + bv_);
  }
}

// ---- Vt[bh][d=64][key=2048] = V_h[key][d] ----
__global__ __launch_bounds__(256) void vtrans(const unsigned short* __restrict__ Pv,
                                              unsigned short* __restrict__ Vt){
  int kt = blockIdx.x, bh = blockIdx.y;
  int b = bh >> 3, h = bh & 7;
  __shared__ unsigned short t[64][65];
  const unsigned short* src = Pv + (size_t)(b*2048 + h*256)*512 + kt*4096;
  for (int i = threadIdx.x; i < 4096; i += 256){ int r = i >> 6, c = i & 63; t[r][c] = src[i]; }
  __syncthreads();
  unsigned short* dst = Vt + (size_t)bh*131072 + kt*64;
  for (int i = threadIdx.x; i < 4096; i += 256){ int d = i >> 6, kk = i & 63; dst[(size_t)d*2048 + kk] = t[kk][d]; }
}

// ---- flash: 8 waves = 4 q-subtiles x 2 KV halves; staged K/V, packed-A output ----
__global__ __launch_bounds__(512) void flash(const unsigned short* __restrict__ Pq,
                                             const unsigned short* __restrict__ Pk,
                                             const unsigned short* __restrict__ Vt,
                                             const float* __restrict__ mf,
                                             unsigned short* __restrict__ aout){
  int qt = blockIdx.x;          // 0..31
  int bh = blockIdx.y;          // 0..15
  int b = bh >> 3, h = bh & 7;
  int w = threadIdx.x >> 6;     // 0..7
  int wq = w & 3, wk = w >> 2;
  int lane = threadIdx.x & 63;
  int lr = lane & 15, lg = lane >> 4;

  const unsigned short* Qh  = Pq + (size_t)(b*2048 + h*256)*512;
  const unsigned short* Kh  = Pk + (size_t)(b*2048 + h*256)*512 + (size_t)wk*65536;  // +1024 keys
  const unsigned short* Vth = Vt + (size_t)bh*131072 + wk*1024;
  const float* mrow = mf + b*2048 + wk*1024;

  __shared__ char smem[65536];
  unsigned short* ktile = (unsigned short*)smem;            // [dbuf 2][wk 2][4096]
  unsigned short* vtile = (unsigned short*)(smem + 32768);  // [dbuf 2][wk 2][4096]
  float* obuf = (float*)smem;                               // [wq 4][lane 64][16] (after loop)
  float* mlb  = (float*)(smem + 16384);                     // [2][wq 4][16]

  int lrow = lane >> 3;
  int lcol = ((lane & 7) ^ lrow) * 8;     // pre-swizzled global source chunk

  int q = qt*64 + wq*16 + lr;
  s16x8 qf0 = *(const s16x8*)(Qh + (size_t)q*64 + lg*8);
  s16x8 qf1 = *(const s16x8*)(Qh + (size_t)q*64 + 32 + lg*8);

  float m2 = -INFINITY, l = 0.f;
  f32x4 accT[4] = {};   // accT[nd][r] = O^T[d=nd*16+lg*4+r][q=lr]
  int swz = (lr & 7) * 16;

#define STAGE(dbuf, kk0) { \
    int i0 = 2*wq, i1 = 2*wq + 1; \
    unsigned short* kd = ktile + ((dbuf)*2 + wk)*4096; \
    unsigned short* vd = vtile + ((dbuf)*2 + wk)*4096; \
    gl_lds16(Kh  + (size_t)((kk0) + 8*i0 + lrow)*64 + lcol, kd + i0*512); \
    gl_lds16(Kh  + (size_t)((kk0) + 8*i1 + lrow)*64 + lcol, kd + i1*512); \
    gl_lds16(Vth + (size_t)(8*i0 + lrow)*2048 + (kk0) + lcol, vd + i0*512); \
    gl_lds16(Vth + (size_t)(8*i1 + lrow)*2048 + (kk0) + lcol, vd + i1*512); }

  STAGE(0, 0)
  __syncthreads();
  int cur = 0;

  for (int t = 0; t < 16; ++t){
    int k0 = t * 64;
    if (t < 15) STAGE(cur ^ 1, k0 + 64)

    const char* kb = (const char*)(ktile + (cur*2 + wk)*4096);
    const char* vb = (const char*)(vtile + (cur*2 + wk)*4096);

    // --- S^T = K Q^T (scale*log2e + mask addend fused) ---
    float s2[4][4];
    __builtin_amdgcn_s_setprio(1);
#pragma unroll
    for (int n = 0; n < 4; ++n){
      int krow = n*16 + lr;
      s16x8 kf0 = *(const s16x8*)(kb + krow*128 + ((lg*16) ^ swz));
      s16x8 kf1 = *(const s16x8*)(kb + krow*128 + ((64 + lg*16) ^ swz));
      f32x4 a = {};
      a = __builtin_amdgcn_mfma_f32_16x16x32_bf16(kf0, qf0, a, 0, 0, 0);
      a = __builtin_amdgcn_mfma_f32_16x16x32_bf16(kf1, qf1, a, 0, 0, 0);
      f32x4 mv = *(const f32x4*)(mrow + k0 + n*16 + lg*4);
#pragma unroll
      for (int r = 0; r < 4; ++r)
        s2[n][r] = __builtin_fmaf(a[r], 0.18033688f, mv[r]);   // log2e/8
    }
    __builtin_amdgcn_s_setprio(0);

    // --- rowmax: in-lane tree + 2 shfls ---
    float t0 = fmaxf(fmaxf(s2[0][0], s2[0][1]), fmaxf(s2[0][2], s2[0][3]));
    float t1 = fmaxf(fmaxf(s2[1][0], s2[1][1]), fmaxf(s2[1][2], s2[1][3]));
    float t2 = fmaxf(fmaxf(s2[2][0], s2[2][1]), fmaxf(s2[2][2], s2[2][3]));
    float t3 = fmaxf(fmaxf(s2[3][0], s2[3][1]), fmaxf(s2[3][2], s2[3][3]));
    float rm = fmaxf(fmaxf(t0, t1), fmaxf(t2, t3));
    rm = fmaxf(rm, __shfl_xor(rm, 16));
    rm = fmaxf(rm, __shfl_xor(rm, 32));
    if (!__all(rm <= m2 + 11.54f)){
      float mn = fmaxf(m2, rm);
      float al = __builtin_amdgcn_exp2f(m2 - mn);
      l *= al;
#pragma unroll
      for (int nd = 0; nd < 4; ++nd)
#pragma unroll
        for (int r = 0; r < 4; ++r) accT[nd][r] *= al;
      m2 = mn;
    }
    // --- P = exp2(S2 - m2): in-register 16x16x16 B-frags ---
    s16x4 pf[4];
#pragma unroll
    for (int n = 0; n < 4; ++n){
      float p0 = __builtin_amdgcn_exp2f(s2[n][0] - m2);
      float p1 = __builtin_amdgcn_exp2f(s2[n][1] - m2);
      float p2 = __builtin_amdgcn_exp2f(s2[n][2] - m2);
      float p3 = __builtin_amdgcn_exp2f(s2[n][3] - m2);
      l += (p0 + p1) + (p2 + p3);
      pf[n] = (s16x4){ (short)bfc(p0), (short)bfc(p1), (short)bfc(p2), (short)bfc(p3) };
    }
    // --- O^T += V^T P^T ---
    __builtin_amdgcn_s_setprio(1);
#pragma unroll
    for (int n = 0; n < 4; ++n){
#pragma unroll
      for (int nd = 0; nd < 4; ++nd){
        int vrow = nd*16 + lr;
        s16x4 vf = *(const s16x4*)(vb + vrow*128 + ((n*32 + lg*8) ^ swz));
        accT[nd] = mfma16(vf, pf[n], accT[nd]);
      }
    }
    __builtin_amdgcn_s_setprio(0);

    __syncthreads();
    cur ^= 1;
  }
#undef STAGE

  // --- l reduce across lane groups ---
  float lt = l + __shfl_xor(l, 16);
  lt += __shfl_xor(lt, 32);

  // --- cross-half merge via LDS (tiles dead; alias) ---
  if (wk == 1){
    if (lg == 0){ mlb[wq*16 + lr] = m2; mlb[64 + wq*16 + lr] = lt; }
#pragma unroll
    for (int nd = 0; nd < 4; ++nd)
      *(f32x4*)&obuf[((size_t)wq*64 + lane)*16 + nd*4] = accT[nd];
  }
  __syncthreads();
  if (wk == 0){
    float m1 = mlb[wq*16 + lr];
    float l1 = mlb[64 + wq*16 + lr];
    float mM = fmaxf(m2, m1);
    float a0 = __builtin_amdgcn_exp2f(m2 - mM);
    float a1 = __builtin_amdgcn_exp2f(m1 - mM);
    float inv = 1.f / (lt*a0 + l1*a1);
    int rt = (b*2048 + q) >> 4;   // row%16 == lr
#pragma unroll
    for (int nd = 0; nd < 4; ++nd){
      f32x4 o1 = *(const f32x4*)&obuf[((size_t)wq*64 + lane)*16 + nd*4];
      int g = h*8 + nd*2 + (lg >> 1);
      u16x4 ov;
#pragma unroll
      for (int r = 0; r < 4; ++r)
        ov[r] = bfc((accT[nd][r]*a0 + o1[r]*a1) * inv);
      // packed-A store: ((rt*16 + kc)*64 + lane')*8 + j
      unsigned short* dp = aout + ((size_t)((rt*16 + (g>>2))*64 + (g&3)*16 + lr))*8 + (lg&1)*4;
      *(u16x4*)dp = ov;
    }
  }
}

// ---- output projection: packed A (from flash) x packed Wm -> fp32 row-major ----
__global__ __launch_bounds__(256) void gemm_out(const unsigned short* __restrict__ Ap,
                                                const unsigned short* __restrict__ Wp,
                                                const float* __restrict__ bias,
                                                float* __restrict__ out){
  int w = threadIdx.x >> 6, lane = threadIdx.x & 63;
  int lr = lane & 15, lg = lane >> 4;
  int rt = blockIdx.x * 4 + w;
  int bn = blockIdx.y;
  f32x4 acc[4] = {};
  const unsigned short* Abase = Ap + ((size_t)rt*8192 + lane*8);
  const unsigned short* Wbase = Wp + ((size_t)bn*32768 + lane*8);
#pragma unroll 4
  for (int kc = 0; kc < 16; ++kc){
    s16x8 af = *(const s16x8*)(Abase + kc*512);
#pragma unroll
    for (int n = 0; n < 4; ++n){
      s16x8 bf = *(const s16x8*)(Wbase + ((size_t)n*16 + kc)*512);
      acc[n] = __builtin_amdgcn_mfma_f32_16x16x32_bf16(af, bf, acc[n], 0, 0, 0);
    }
  }
  int orow = rt*16 + lg*4;
#pragma unroll
  for (int n = 0; n < 4; ++n){
    int col = bn*64 + n*16 + lr;
    float bv_ = bias[col];
#pragma unroll
    for (int r = 0; r < 4; ++r)
      out[(size_t)(orow + r)*512 + col] = acc[n][r] + bv_;
  }
}

extern "C" void kernel_launch(void* const* d_in, const int* in_sizes, int n_in,
                              void* d_out, int out_size, void* d_ws, size_t ws_size,
                              hipStream_t stream) {
  const float* q  = (const float*)d_in[0];
  const float* k  = (const float*)d_in[1];
  const float* v  = (const float*)d_in[2];
  const unsigned char* mask = (const unsigned char*)d_in[3];
  const float* Wq = (const float*)d_in[4];
  const float* Wk = (const float*)d_in[5];
  const float* Wv = (const float*)d_in[6];
  const float* Wm = (const float*)d_in[7];
  const float* bq = (const float*)d_in[8];
  const float* bk = (const float*)d_in[9];
  const float* bv = (const float*)d_in[10];
  const float* bm = (const float*)d_in[11];

  unsigned short* ws = (unsigned short*)d_ws;
  unsigned short* WP   = ws;                       // 4 x 262144 (packed weights)
  float*          MF   = (float*)(ws + 1048576);   // 4096 floats
  unsigned short* AP   = ws + 1056768;             // 3 x 2097152 (packed bf16 qkv)
  unsigned short* PQ   = ws + 7348224;             // 3 x 2097152 (row-major Pq,Pk,Pv)
  unsigned short* VT   = ws + 13639680;            // 2097152
  unsigned short* AO   = ws + 15736832;            // 2097152 (packed attn out)

  cvt_qkv<<<dim3(1024, 3), 256, 0, stream>>>(q, k, v, AP);
  wcvt<<<dim3(128, 5), 256, 0, stream>>>(Wq, Wk, Wv, Wm, mask, WP, MF);
  proj_gemm<<<dim3(64, 8, 3), 256, 0, stream>>>(AP, WP, bq, bk, bv, PQ);
  vtrans<<<dim3(32, 16), 256, 0, stream>>>(PQ + 2*2097152, VT);
  flash<<<dim3(32, 16), 512, 0, stream>>>(PQ, PQ + 2097152, VT, MF, AO);
  gemm_out<<<dim3(64, 8), 256, 0, stream>>>(AO, WP + 3*262144, bm, (float*)d_out);
}